// Round 4
// baseline (726.033 us; speedup 1.0000x reference)
//
#include <hip/hip_runtime.h>

#define B_TOT 16384
#define T_STEPS 128
#define F_IN 29
#define K_HID 512
#define NW 4        // waves per block (node dimension split 4 ways)
#define NTILE 8     // node tiles per wave = 512 / (16*NW)
#define XS 29       // sX row stride == F_IN; cols 29..31 are implicit zeros

typedef __attribute__((ext_vector_type(8))) short short8;   // 8 bf16 (MFMA A/B frag)
typedef __attribute__((ext_vector_type(4))) float floatx4;  // MFMA C/D frag
typedef __attribute__((ext_vector_type(2))) float f32x2;    // packed f32 (v_pk_*)

__device__ __forceinline__ short bf16_hi_bits(float x) {
    return (short)(__float_as_uint(x) >> 16);
}
__device__ __forceinline__ float bf16_hi_f(float x) {
    return __uint_as_float(__float_as_uint(x) & 0xffff0000u);
}
// bit-identical per component to v2's fast_tanh: e=__expf(2x); 1-2*rcp(e+1)
__device__ __forceinline__ f32x2 tanh2(f32x2 x) {
    f32x2 a = x + x;
    f32x2 e;
    e.x = __expf(a.x);
    e.y = __expf(a.y);
    f32x2 d = e + 1.0f;
    f32x2 r;
    r.x = __builtin_amdgcn_rcpf(d.x);
    r.y = __builtin_amdgcn_rcpf(d.y);
    return 1.0f - 2.0f * r;
}

// Rank-3 feedback decomposition, conservative form:
//   base(t) = b1 + MFMA(x(t) with fb columns ZEROED)   <- pure function of x(t),
//             computed at the TAIL of iteration t-1 (off the critical path).
//   h(t)    = base(t) + w29*fb0(t) + w30*fb1(t) + w31*fb2(t)   <- ALL fb terms
//             applied in the body of iteration t, post-combine, exact f32 FMA
//             (same point v2 injected fb; no fb state crosses the tail).
// Per-step critical path: barrier -> pp read -> fbn -> 3 pk_fma -> tanh -> reduce.
__global__ __launch_bounds__(256, 2)
void narx_v4(const float* __restrict__ X,   // [B][T][29]
             const float* __restrict__ y0,  // [B][3]
             const float* __restrict__ W1,  // [32][512]
             const float* __restrict__ b1,  // [512]
             const float* __restrict__ W2,  // [512]
             const float* __restrict__ b2,  // [1]
             float* __restrict__ out)       // [B][T]
{
    __shared__ float sX[2][16 * XS];            // 3712 B
    __shared__ float pp[2][NW][16];             // 512 B
    __shared__ short8 sWlo[NW * NTILE * 64];    // 32768 B -> total 36992 B

    const int tid  = threadIdx.x;       // 0..255
    const int wv   = tid >> 6;          // wave id 0..3
    const int lane = tid & 63;
    const int q    = lane >> 4;         // 0..3
    const int m    = lane & 15;         // batch row (A/C) and node col (B)
    const int q4   = q * 4;
    const size_t row0 = (size_t)blockIdx.x * 16;

    const float* W1r29 = W1 + 29 * K_HID;
    const float* W1r30 = W1 + 30 * K_HID;
    const float* W1r31 = W1 + 31 * K_HID;
    const int nodeBase = wv * (NTILE * 16) + m;

    // ---- one-time: W1 B-frags for k=0..28 (hi in regs, lo in LDS) ----
    short8 whi[NTILE];
    #pragma unroll
    for (int nt = 0; nt < NTILE; ++nt) {
        int node = nodeBase + nt * 16;
        short8 lo;
        #pragma unroll
        for (int j = 0; j < 8; ++j) {
            int k = q * 8 + j;
            float v  = (k < F_IN) ? W1[k * K_HID + node] : 0.f;
            float hf = bf16_hi_f(v);
            whi[nt][j] = bf16_hi_bits(v);
            lo[j]      = bf16_hi_bits(v - hf);
        }
        sWlo[(wv * NTILE + nt) * 64 + lane] = lo;
    }
    const float b2v = b2[0];

    // feedback state for rows q4+0..3 (lags 0,1,2), replicated over m and wv
    const float* y0r = y0 + (row0 + q4) * 3;
    float4 fbr0 = make_float4(y0r[0], y0r[3], y0r[6], y0r[9]);
    float4 fbr1 = make_float4(y0r[1], y0r[4], y0r[7], y0r[10]);
    float4 fbr2 = make_float4(y0r[2], y0r[5], y0r[8], y0r[11]);

    // ---- X staging: 464 floats/step over 256 threads; LDS elem index = flat f ----
    const float* Xblk = X + row0 * (T_STEPS * F_IN);
    const int f0 = tid, f1 = tid + 256;
    const bool v1 = (f1 < 16 * F_IN);
    const int r0 = f0 / F_IN, c0 = f0 - r0 * F_IN;
    const int r1 = f1 / F_IN, c1 = f1 - r1 * F_IN;
    const int xo0 = r0 * (T_STEPS * F_IN) + c0;
    const int xo1 = r1 * (T_STEPS * F_IN) + c1;

    // stage X(0) and X(1)
    sX[0][f0] = Xblk[xo0];
    if (v1) sX[0][f1] = Xblk[xo1];
    sX[1][f0] = Xblk[xo0 + F_IN];
    if (v1) sX[1][f1] = Xblk[xo1 + F_IN];
    __syncthreads();   // publish sX[0], sX[1], sWlo

    f32x2 c01[NTILE], c23[NTILE];   // base(t+1): persists across the barrier

    // base(buf-step): A from sX[buf] (k>=29 -> 0), C-init = b1, 3 MFMAs
    auto compute_base = [&](int buf) {
        const float* sxm = &sX[buf][m * XS];
        short8 ahi, alo;
        #pragma unroll
        for (int j = 0; j < 8; ++j) {
            int k = q * 8 + j;
            float xj = sxm[(k < F_IN) ? k : 0];
            if (k >= F_IN) xj = 0.f;
            float hf = bf16_hi_f(xj);
            ahi[j] = bf16_hi_bits(xj);
            alo[j] = bf16_hi_bits(xj - hf);
        }
        #pragma unroll
        for (int nt = 0; nt < NTILE; ++nt) {
            float bb = b1[nodeBase + nt * 16];     // L1-hot
            floatx4 c = {bb, bb, bb, bb};
            short8 wl = sWlo[(wv * NTILE + nt) * 64 + lane];
            c = __builtin_amdgcn_mfma_f32_16x16x32_bf16(ahi, whi[nt], c, 0, 0, 0);
            c = __builtin_amdgcn_mfma_f32_16x16x32_bf16(ahi, wl,      c, 0, 0, 0);
            c = __builtin_amdgcn_mfma_f32_16x16x32_bf16(alo, whi[nt], c, 0, 0, 0);
            // C/D: col(node) = lane&15, row(batch) = q*4 + reg
            c01[nt] = (f32x2){c[0], c[1]};
            c23[nt] = (f32x2){c[2], c[3]};
        }
    };

    compute_base(0);   // base(0)

    float4 pv = make_float4(0.f, 0.f, 0.f, 0.f);

    for (int t = 0; t < T_STEPS; ++t) {
        const int cur = t & 1;
        __syncthreads();   // publishes pp(t-1) and sX writes from body(t-1)

        // early-issue loads: fb weights (L1-hot) + X(t+2) prefetch
        float w29t[NTILE], w30t[NTILE], w31t[NTILE], w2t[NTILE];
        #pragma unroll
        for (int nt = 0; nt < NTILE; ++nt) {
            const int no = nodeBase + nt * 16;
            w29t[nt] = W1r29[no];
            w30t[nt] = W1r30[no];
            w31t[nt] = W1r31[no];
            w2t[nt]  = W2[no];
        }
        const int tl = (t + 2 < T_STEPS) ? t + 2 : T_STEPS - 1;
        float xp0 = Xblk[xo0 + tl * F_IN];
        float xp1 = v1 ? Xblk[xo1 + tl * F_IN] : 0.f;

        // ---- combine pred(t-1); shift feedback; output ----
        if (t > 0) {
            const int pb = cur ^ 1;
            float4 s0 = *(const float4*)&pp[pb][0][q4];
            float4 s1 = *(const float4*)&pp[pb][1][q4];
            float4 s2 = *(const float4*)&pp[pb][2][q4];
            float4 s3 = *(const float4*)&pp[pb][3][q4];
            float4 fbn = (s0 + s1) + (s2 + s3);
            fbn.x += b2v; fbn.y += b2v; fbn.z += b2v; fbn.w += b2v;
            fbr2 = fbr1; fbr1 = fbr0; fbr0 = fbn;
            if (wv == 0 && m < 4) {        // lane (q, m<4) owns row q4+m
                float po = m == 0 ? fbn.x : m == 1 ? fbn.y
                         : m == 2 ? fbn.z : fbn.w;
                pv = make_float4(pv.y, pv.z, pv.w, po);
                if (((t - 1) & 3) == 3)
                    *(float4*)&out[(row0 + q4 + m) * T_STEPS + (t - 4)] = pv;
            }
        }

        // ---- h = base + w29*fb0 + w30*fb1 + w31*fb2 (exact f32); tanh; W2 ----
        f32x2 fb001 = {fbr0.x, fbr0.y}, fb023 = {fbr0.z, fbr0.w};
        f32x2 fb101 = {fbr1.x, fbr1.y}, fb123 = {fbr1.z, fbr1.w};
        f32x2 fb201 = {fbr2.x, fbr2.y}, fb223 = {fbr2.z, fbr2.w};
        f32x2 pa01 = {0.f, 0.f}, pa23 = {0.f, 0.f};
        #pragma unroll
        for (int nt = 0; nt < NTILE; ++nt) {
            f32x2 h01 = c01[nt] + fb001 * w29t[nt] + fb101 * w30t[nt]
                                 + fb201 * w31t[nt];
            f32x2 h23 = c23[nt] + fb023 * w29t[nt] + fb123 * w30t[nt]
                                 + fb223 * w31t[nt];
            f32x2 t01 = tanh2(h01);
            f32x2 t23 = tanh2(h23);
            pa01 += t01 * w2t[nt];
            pa23 += t23 * w2t[nt];
        }

        // ---- in-wave reduce over the 16 node cols (lane bits 0..3) ----
        #pragma unroll
        for (int mask = 1; mask <= 8; mask <<= 1) {
            pa01.x += __shfl_xor(pa01.x, mask, 64);
            pa01.y += __shfl_xor(pa01.y, mask, 64);
            pa23.x += __shfl_xor(pa23.x, mask, 64);
            pa23.y += __shfl_xor(pa23.y, mask, 64);
        }
        if (m == 0)
            *(float4*)&pp[cur][wv][q4] =
                make_float4(pa01.x, pa01.y, pa23.x, pa23.y);

        // ---- stage X(t+2) into sX[cur] (its X(t) content is dead) ----
        sX[cur][f0] = xp0;
        if (v1) sX[cur][f1] = xp1;

        // ---- tail: base(t+1) = b1 + x(t+1)-MFMA, off the critical path ----
        if (t + 1 < T_STEPS)
            compute_base(cur ^ 1);
    }

    // ---- tail: combine pred(127), flush last output quad ----
    __syncthreads();
    if (wv == 0 && m < 4) {
        const int pb = (T_STEPS - 1) & 1;
        float4 s0 = *(const float4*)&pp[pb][0][q4];
        float4 s1 = *(const float4*)&pp[pb][1][q4];
        float4 s2 = *(const float4*)&pp[pb][2][q4];
        float4 s3 = *(const float4*)&pp[pb][3][q4];
        float4 fbn = (s0 + s1) + (s2 + s3);
        fbn.x += b2v; fbn.y += b2v; fbn.z += b2v; fbn.w += b2v;
        float po = m == 0 ? fbn.x : m == 1 ? fbn.y : m == 2 ? fbn.z : fbn.w;
        pv = make_float4(pv.y, pv.z, pv.w, po);
        *(float4*)&out[(row0 + q4 + m) * T_STEPS + (T_STEPS - 4)] = pv;
    }
}

extern "C" void kernel_launch(void* const* d_in, const int* in_sizes, int n_in,
                              void* d_out, int out_size, void* d_ws, size_t ws_size,
                              hipStream_t stream) {
    const float* X  = (const float*)d_in[0];
    const float* y0 = (const float*)d_in[1];
    const float* W1 = (const float*)d_in[2];
    const float* b1 = (const float*)d_in[3];
    const float* W2 = (const float*)d_in[4];
    const float* b2 = (const float*)d_in[5];
    float* out = (float*)d_out;

    dim3 grid(B_TOT / 16);
    dim3 block(64 * NW);
    narx_v4<<<grid, block, 0, stream>>>(X, y0, W1, b1, W2, b2, out);
}

// Round 5
// 644.788 us; speedup vs baseline: 1.1260x; 1.1260x over previous
//
#include <hip/hip_runtime.h>

#define B_TOT 16384
#define T_STEPS 128
#define F_IN 29
#define K_HID 512
#define NW 4        // waves per block (node dimension split 4 ways)
#define NTILE 8     // node tiles per wave = 512 / (16*NW)

typedef __attribute__((ext_vector_type(8))) short short8;   // 8 bf16 (MFMA A/B frag)
typedef __attribute__((ext_vector_type(4))) float floatx4;  // MFMA C/D frag
typedef __attribute__((ext_vector_type(2))) float f32x2;    // packed f32 (v_pk_*)

__device__ __forceinline__ short bf16_hi_bits(float x) {
    return (short)(__float_as_uint(x) >> 16);
}
__device__ __forceinline__ float bf16_hi_f(float x) {
    return __uint_as_float(__float_as_uint(x) & 0xffff0000u);
}
// per component identical to v2's fast_tanh: e=__expf(2x); 1-2*rcp(e+1)
__device__ __forceinline__ f32x2 tanh2(f32x2 x) {
    f32x2 a = x + x;
    f32x2 e;
    e.x = __expf(a.x);
    e.y = __expf(a.y);
    f32x2 d = e + 1.0f;
    f32x2 r;
    r.x = __builtin_amdgcn_rcpf(d.x);
    r.y = __builtin_amdgcn_rcpf(d.y);
    return 1.0f - 2.0f * r;
}

// v2 structure (best: 463us) with the VALU fat trimmed:
//  - A-fragments pre-converted to bf16 hi/lo AT STAGE TIME by the 256 staging
//    threads (once per element) into MFMA-layout LDS tables; per-wave A-build
//    collapses from ~50 convert/pack instrs to 2x ds_read_b128 + a 3-element
//    fb patch on q==3 lanes (same inject point & math as v2).
//  - all f32 elementwise math packed as float2 -> v_pk_{add,mul,fma}_f32.
// Numerics are bit-identical to v2 (same bf16x3 MFMA, same truncation splits,
// same tanh op sequence). Barrier/ping-pong scheme unchanged (depth-1).
__global__ __launch_bounds__(256, 2)
void narx_v5(const float* __restrict__ X,   // [B][T][29]
             const float* __restrict__ y0,  // [B][3]
             const float* __restrict__ W1,  // [32][512]
             const float* __restrict__ b1,  // [512]
             const float* __restrict__ W2,  // [512]
             const float* __restrict__ b2,  // [1]
             float* __restrict__ out)       // [B][T]
{
    // sA[buf][0]=hi, sA[buf][1]=lo; element (row m, k) at [m*32+k]
    __shared__ __align__(16) short sA[2][2][16 * 32];   // 4096 B
    __shared__ float pp[2][NW][16];                     // 512 B
    __shared__ short8 sWlo[NW * NTILE * 64];            // 32768 B -> 37376 B total

    const int tid  = threadIdx.x;       // 0..255
    const int wv   = tid >> 6;          // wave id 0..3
    const int lane = tid & 63;
    const int q    = lane >> 4;         // 0..3
    const int m    = lane & 15;         // batch row (A/C) and node col (B)
    const size_t row0 = (size_t)blockIdx.x * 16;

    // ---- one-time: this wave's W1 B-frags (hi in regs, lo in LDS) ----
    short8 whi[NTILE];
    float b1v[NTILE], w2v[NTILE];
    #pragma unroll
    for (int nt = 0; nt < NTILE; ++nt) {
        int node = wv * (NTILE * 16) + nt * 16 + m;
        short8 lo;
        #pragma unroll
        for (int j = 0; j < 8; ++j) {
            int k = q * 8 + j;
            float v  = W1[k * K_HID + node];
            float hf = bf16_hi_f(v);
            whi[nt][j] = bf16_hi_bits(v);
            lo[j]      = bf16_hi_bits(v - hf);
        }
        sWlo[(wv * NTILE + nt) * 64 + lane] = lo;
        b1v[nt] = b1[node];
        w2v[nt] = W2[node];
    }
    const float b2v = b2[0];

    // per-lane feedback for row m (replicated over q and wv), v2-identical
    float fb0 = y0[(row0 + m) * 3 + 0];
    float fb1 = y0[(row0 + m) * 3 + 1];
    float fb2 = y0[(row0 + m) * 3 + 2];

    // ---- X staging: 464 elems/step over 256 threads (<=2 each) ----
    const float* Xblk = X + row0 * (T_STEPS * F_IN);
    const int f0 = tid, f1 = tid + 256;
    const bool v1 = (f1 < 16 * F_IN);
    const int r0 = f0 / F_IN, c0 = f0 - r0 * F_IN;
    const int r1 = f1 / F_IN, c1 = f1 - r1 * F_IN;
    const int xo0 = r0 * (T_STEPS * F_IN) + c0;
    const int xo1 = r1 * (T_STEPS * F_IN) + c1;
    const int a0i = r0 * 32 + c0;
    const int a1i = r1 * 32 + c1;

    // stage X(0): convert to hi/lo at stage time
    {
        float a0 = Xblk[xo0];
        float a1 = v1 ? Xblk[xo1] : 0.f;
        float h0 = bf16_hi_f(a0), h1 = bf16_hi_f(a1);
        sA[0][0][a0i] = bf16_hi_bits(a0);
        sA[0][1][a0i] = bf16_hi_bits(a0 - h0);
        if (v1) {
            sA[0][0][a1i] = bf16_hi_bits(a1);
            sA[0][1][a1i] = bf16_hi_bits(a1 - h1);
        }
    }

    float4 pv = make_float4(0.f, 0.f, 0.f, 0.f);

    for (int t = 0; t < T_STEPS; ++t) {
        const int cur = t & 1;
        __syncthreads();   // publishes pp(t-1), sA[cur]=X(t)
                           // (t=0: also covers sWlo + sA[0] prologue writes)

        // issue global prefetch of X(t+1) (converted+written at step end)
        const int tn = (t + 1 < T_STEPS) ? (t + 1) : t;
        float xp0 = Xblk[xo0 + tn * F_IN];
        float xp1 = v1 ? Xblk[xo1 + tn * F_IN] : 0.f;

        // ---- combine pred(t-1); shift feedback; output (v2-identical) ----
        if (t > 0) {
            const int pb = cur ^ 1;
            float fbn = pp[pb][0][m] + pp[pb][1][m]
                      + pp[pb][2][m] + pp[pb][3][m] + b2v;
            fb2 = fb1; fb1 = fb0; fb0 = fbn;
            if (wv == 0 && m < 4) {        // lane (q, m<4) owns row q*4+m
                const int ro = q * 4 + m;
                float po = pp[pb][0][ro] + pp[pb][1][ro]
                         + pp[pb][2][ro] + pp[pb][3][ro] + b2v;
                pv = make_float4(pv.y, pv.z, pv.w, po);
                if (((t - 1) & 3) == 3)
                    *(float4*)&out[(row0 + ro) * T_STEPS + (t - 4)] = pv;
            }
        }

        // ---- A-frag: 2x ds_read_b128 + fb patch on q==3 lanes ----
        short8 ahi = *(const short8*)&sA[cur][0][m * 32 + q * 8];
        short8 alo = *(const short8*)&sA[cur][1][m * 32 + q * 8];
        if (q == 3) {   // k = 29,30,31 <- fb0,fb1,fb2 (lane-local, row m)
            float h;
            h = bf16_hi_f(fb0); ahi[5] = bf16_hi_bits(fb0); alo[5] = bf16_hi_bits(fb0 - h);
            h = bf16_hi_f(fb1); ahi[6] = bf16_hi_bits(fb1); alo[6] = bf16_hi_bits(fb1 - h);
            h = bf16_hi_f(fb2); ahi[7] = bf16_hi_bits(fb2); alo[7] = bf16_hi_bits(fb2 - h);
        }

        // ---- 8 node tiles: bf16x3 MFMA + packed tanh + W2 partial ----
        f32x2 pa01 = {0.f, 0.f}, pa23 = {0.f, 0.f};
        #pragma unroll
        for (int nt = 0; nt < NTILE; ++nt) {
            const float bb = b1v[nt];
            floatx4 c = {bb, bb, bb, bb};
            short8 wl = sWlo[(wv * NTILE + nt) * 64 + lane];
            c = __builtin_amdgcn_mfma_f32_16x16x32_bf16(ahi, whi[nt], c, 0, 0, 0);
            c = __builtin_amdgcn_mfma_f32_16x16x32_bf16(ahi, wl,      c, 0, 0, 0);
            c = __builtin_amdgcn_mfma_f32_16x16x32_bf16(alo, whi[nt], c, 0, 0, 0);
            // C/D: col(node) = lane&15, row(batch) = q*4 + reg
            f32x2 t01 = tanh2((f32x2){c[0], c[1]});
            f32x2 t23 = tanh2((f32x2){c[2], c[3]});
            pa01 += t01 * w2v[nt];
            pa23 += t23 * w2v[nt];
        }

        // ---- in-wave reduce over the 16 node cols (lane bits 0..3) ----
        #pragma unroll
        for (int mask = 1; mask <= 8; mask <<= 1) {
            f32x2 o01, o23;
            o01.x = __shfl_xor(pa01.x, mask, 64);
            o01.y = __shfl_xor(pa01.y, mask, 64);
            o23.x = __shfl_xor(pa23.x, mask, 64);
            o23.y = __shfl_xor(pa23.y, mask, 64);
            pa01 += o01;
            pa23 += o23;
        }
        if (m == 0)
            *(float4*)&pp[cur][wv][q * 4] =
                make_float4(pa01.x, pa01.y, pa23.x, pa23.y);

        // ---- stage X(t+1): convert hi/lo, write into the other buffer ----
        {
            float h0 = bf16_hi_f(xp0), h1 = bf16_hi_f(xp1);
            sA[cur ^ 1][0][a0i] = bf16_hi_bits(xp0);
            sA[cur ^ 1][1][a0i] = bf16_hi_bits(xp0 - h0);
            if (v1) {
                sA[cur ^ 1][0][a1i] = bf16_hi_bits(xp1);
                sA[cur ^ 1][1][a1i] = bf16_hi_bits(xp1 - h1);
            }
        }
    }

    // ---- tail: combine pred(127), flush last output quad ----
    __syncthreads();
    if (wv == 0 && m < 4) {
        const int pb = (T_STEPS - 1) & 1;
        const int ro = q * 4 + m;
        float po = pp[pb][0][ro] + pp[pb][1][ro]
                 + pp[pb][2][ro] + pp[pb][3][ro] + b2v;
        pv = make_float4(pv.y, pv.z, pv.w, po);
        *(float4*)&out[(row0 + ro) * T_STEPS + (T_STEPS - 4)] = pv;
    }
}

extern "C" void kernel_launch(void* const* d_in, const int* in_sizes, int n_in,
                              void* d_out, int out_size, void* d_ws, size_t ws_size,
                              hipStream_t stream) {
    const float* X  = (const float*)d_in[0];
    const float* y0 = (const float*)d_in[1];
    const float* W1 = (const float*)d_in[2];
    const float* b1 = (const float*)d_in[3];
    const float* W2 = (const float*)d_in[4];
    const float* b2 = (const float*)d_in[5];
    float* out = (float*)d_out;

    dim3 grid(B_TOT / 16);   // 1024 blocks x 4 waves; 4 blocks/CU (even grid)
    dim3 block(64 * NW);
    narx_v5<<<grid, block, 0, stream>>>(X, y0, W1, b1, W2, b2, out);
}

// Round 6
// 580.178 us; speedup vs baseline: 1.2514x; 1.1114x over previous
//
#include <hip/hip_runtime.h>

#define B_TOT 16384
#define T_STEPS 128
#define F_IN 29
#define K_HID 512
#define NW 4        // waves per block (node dimension split 4 ways)
#define NTILE 8     // node tiles per wave = 512 / (16*NW)

typedef __attribute__((ext_vector_type(8))) short short8;   // 8 bf16 (MFMA A/B frag)
typedef __attribute__((ext_vector_type(4))) float floatx4;  // MFMA C/D frag
typedef __attribute__((ext_vector_type(2))) float f32x2;    // packed f32 (v_pk_*)

__device__ __forceinline__ short bf16_hi_bits(float x) {
    return (short)(__float_as_uint(x) >> 16);
}
__device__ __forceinline__ float bf16_hi_f(float x) {
    return __uint_as_float(__float_as_uint(x) & 0xffff0000u);
}

// tanh pair, trans-minimized: 3 trans/pair (2 exp + 1 shared rcp) vs v5's
// (2 mul + 2 exp + 2 rcp).  exp(2x) = exp2(x * 2log2e), arg scale folded
// into one pk_mul; 1/d0 = d1*rcp(d0*d1), 1/d1 = d0*rcp(d0*d1).
__device__ __forceinline__ f32x2 tanh2(f32x2 x) {
    f32x2 a = x * 2.88539008177793f;    // 2*log2(e)
    f32x2 e;
    e.x = __builtin_amdgcn_exp2f(a.x);
    e.y = __builtin_amdgcn_exp2f(a.y);
    f32x2 d = e + 1.0f;
    float rp = __builtin_amdgcn_rcpf(d.x * d.y);
    f32x2 r = {d.y * rp, d.x * rp};
    return 1.0f - 2.0f * r;
}

// sum over each 16-lane row via DPP row_shr prefix (VALU-only, no DS);
// result valid at lane 15 of each row.
__device__ __forceinline__ float dpp_sum16(float v) {
    int t;
    t = __builtin_amdgcn_update_dpp(0, __float_as_int(v), 0x111, 0xF, 0xF, true);
    v += __int_as_float(t);
    t = __builtin_amdgcn_update_dpp(0, __float_as_int(v), 0x112, 0xF, 0xF, true);
    v += __int_as_float(t);
    t = __builtin_amdgcn_update_dpp(0, __float_as_int(v), 0x114, 0xF, 0xF, true);
    v += __int_as_float(t);
    t = __builtin_amdgcn_update_dpp(0, __float_as_int(v), 0x118, 0xF, 0xF, true);
    v += __int_as_float(t);
    return v;
}

// v5 structure (barriers/ping-pong/numerics identical) with the trans pipe
// and the reduce's DS serial chain trimmed:
//  - tanh: exp2-direct + shared rcp  -> trans 64 -> 48 per wave-step
//  - reduce: ds_swizzle butterfly -> DPP row_shr prefix (writer lane m==15)
//  - pp transposed to [row][wave]: post-barrier combine is 1 ds_read_b128
__global__ __launch_bounds__(256, 2)
void narx_v6(const float* __restrict__ X,   // [B][T][29]
             const float* __restrict__ y0,  // [B][3]
             const float* __restrict__ W1,  // [32][512]
             const float* __restrict__ b1,  // [512]
             const float* __restrict__ W2,  // [512]
             const float* __restrict__ b2,  // [1]
             float* __restrict__ out)       // [B][T]
{
    // sA[buf][0]=hi, sA[buf][1]=lo; element (row m, k) at [m*32+k]
    __shared__ __align__(16) short sA[2][2][16 * 32];   // 4096 B
    __shared__ __align__(16) float pp[2][16][NW];       // 512 B, [row][wave]
    __shared__ short8 sWlo[NW * NTILE * 64];            // 32768 B -> 37376 B

    const int tid  = threadIdx.x;       // 0..255
    const int wv   = tid >> 6;          // wave id 0..3
    const int lane = tid & 63;
    const int q    = lane >> 4;         // 0..3
    const int m    = lane & 15;         // batch row (A/C) and node col (B)
    const size_t row0 = (size_t)blockIdx.x * 16;

    // ---- one-time: this wave's W1 B-frags (hi in regs, lo in LDS) ----
    short8 whi[NTILE];
    float b1v[NTILE], w2v[NTILE];
    #pragma unroll
    for (int nt = 0; nt < NTILE; ++nt) {
        int node = wv * (NTILE * 16) + nt * 16 + m;
        short8 lo;
        #pragma unroll
        for (int j = 0; j < 8; ++j) {
            int k = q * 8 + j;
            float v  = W1[k * K_HID + node];
            float hf = bf16_hi_f(v);
            whi[nt][j] = bf16_hi_bits(v);
            lo[j]      = bf16_hi_bits(v - hf);
        }
        sWlo[(wv * NTILE + nt) * 64 + lane] = lo;
        b1v[nt] = b1[node];
        w2v[nt] = W2[node];
    }
    const float b2v = b2[0];

    // per-lane feedback for row m (replicated over q and wv), v2-identical
    float fb0 = y0[(row0 + m) * 3 + 0];
    float fb1 = y0[(row0 + m) * 3 + 1];
    float fb2 = y0[(row0 + m) * 3 + 2];

    // ---- X staging: 464 elems/step over 256 threads (<=2 each) ----
    const float* Xblk = X + row0 * (T_STEPS * F_IN);
    const int f0 = tid, f1 = tid + 256;
    const bool v1 = (f1 < 16 * F_IN);
    const int r0 = f0 / F_IN, c0 = f0 - r0 * F_IN;
    const int r1 = f1 / F_IN, c1 = f1 - r1 * F_IN;
    const int xo0 = r0 * (T_STEPS * F_IN) + c0;
    const int xo1 = r1 * (T_STEPS * F_IN) + c1;
    const int a0i = r0 * 32 + c0;
    const int a1i = r1 * 32 + c1;

    // stage X(0): convert to hi/lo at stage time
    {
        float a0 = Xblk[xo0];
        float a1 = v1 ? Xblk[xo1] : 0.f;
        float h0 = bf16_hi_f(a0), h1 = bf16_hi_f(a1);
        sA[0][0][a0i] = bf16_hi_bits(a0);
        sA[0][1][a0i] = bf16_hi_bits(a0 - h0);
        if (v1) {
            sA[0][0][a1i] = bf16_hi_bits(a1);
            sA[0][1][a1i] = bf16_hi_bits(a1 - h1);
        }
    }

    float4 pv = make_float4(0.f, 0.f, 0.f, 0.f);

    for (int t = 0; t < T_STEPS; ++t) {
        const int cur = t & 1;
        __syncthreads();   // publishes pp(t-1), sA[cur]=X(t)
                           // (t=0: also covers sWlo + sA[0] prologue writes)

        // issue global prefetch of X(t+1) (converted+written at step end)
        const int tn = (t + 1 < T_STEPS) ? (t + 1) : t;
        float xp0 = Xblk[xo0 + tn * F_IN];
        float xp1 = v1 ? Xblk[xo1 + tn * F_IN] : 0.f;

        // ---- combine pred(t-1); shift feedback; output ----
        if (t > 0) {
            const int pb = cur ^ 1;
            float4 s = *(const float4*)&pp[pb][m][0];
            float fbn = (s.x + s.y) + (s.z + s.w) + b2v;
            fb2 = fb1; fb1 = fb0; fb0 = fbn;
            if (wv == 0 && m < 4) {        // lane (q, m<4) owns row q*4+m
                const int ro = q * 4 + m;
                float4 so = *(const float4*)&pp[pb][ro][0];
                float po = (so.x + so.y) + (so.z + so.w) + b2v;
                pv = make_float4(pv.y, pv.z, pv.w, po);
                if (((t - 1) & 3) == 3)
                    *(float4*)&out[(row0 + ro) * T_STEPS + (t - 4)] = pv;
            }
        }

        // ---- A-frag: 2x ds_read_b128 + fb patch on q==3 lanes ----
        short8 ahi = *(const short8*)&sA[cur][0][m * 32 + q * 8];
        short8 alo = *(const short8*)&sA[cur][1][m * 32 + q * 8];
        if (q == 3) {   // k = 29,30,31 <- fb0,fb1,fb2 (lane-local, row m)
            float h;
            h = bf16_hi_f(fb0); ahi[5] = bf16_hi_bits(fb0); alo[5] = bf16_hi_bits(fb0 - h);
            h = bf16_hi_f(fb1); ahi[6] = bf16_hi_bits(fb1); alo[6] = bf16_hi_bits(fb1 - h);
            h = bf16_hi_f(fb2); ahi[7] = bf16_hi_bits(fb2); alo[7] = bf16_hi_bits(fb2 - h);
        }

        // ---- 8 node tiles: bf16x3 MFMA + packed tanh + W2 partial ----
        f32x2 pa01 = {0.f, 0.f}, pa23 = {0.f, 0.f};
        #pragma unroll
        for (int nt = 0; nt < NTILE; ++nt) {
            const float bb = b1v[nt];
            floatx4 c = {bb, bb, bb, bb};
            short8 wl = sWlo[(wv * NTILE + nt) * 64 + lane];
            c = __builtin_amdgcn_mfma_f32_16x16x32_bf16(ahi, whi[nt], c, 0, 0, 0);
            c = __builtin_amdgcn_mfma_f32_16x16x32_bf16(ahi, wl,      c, 0, 0, 0);
            c = __builtin_amdgcn_mfma_f32_16x16x32_bf16(alo, whi[nt], c, 0, 0, 0);
            // C/D: col(node) = lane&15, row(batch) = q*4 + reg
            f32x2 t01 = tanh2((f32x2){c[0], c[1]});
            f32x2 t23 = tanh2((f32x2){c[2], c[3]});
            pa01 += t01 * w2v[nt];
            pa23 += t23 * w2v[nt];
        }

        // ---- reduce over the 16 node cols: DPP prefix, sum lands at m==15 ----
        pa01.x = dpp_sum16(pa01.x);
        pa01.y = dpp_sum16(pa01.y);
        pa23.x = dpp_sum16(pa23.x);
        pa23.y = dpp_sum16(pa23.y);
        if (m == 15) {   // rows q*4+0..3, one slot per wave
            pp[cur][q * 4 + 0][wv] = pa01.x;
            pp[cur][q * 4 + 1][wv] = pa01.y;
            pp[cur][q * 4 + 2][wv] = pa23.x;
            pp[cur][q * 4 + 3][wv] = pa23.y;
        }

        // ---- stage X(t+1): convert hi/lo, write into the other buffer ----
        {
            float h0 = bf16_hi_f(xp0), h1 = bf16_hi_f(xp1);
            sA[cur ^ 1][0][a0i] = bf16_hi_bits(xp0);
            sA[cur ^ 1][1][a0i] = bf16_hi_bits(xp0 - h0);
            if (v1) {
                sA[cur ^ 1][0][a1i] = bf16_hi_bits(xp1);
                sA[cur ^ 1][1][a1i] = bf16_hi_bits(xp1 - h1);
            }
        }
    }

    // ---- tail: combine pred(127), flush last output quad ----
    __syncthreads();
    if (wv == 0 && m < 4) {
        const int pb = (T_STEPS - 1) & 1;
        const int ro = q * 4 + m;
        float4 so = *(const float4*)&pp[pb][ro][0];
        float po = (so.x + so.y) + (so.z + so.w) + b2v;
        pv = make_float4(pv.y, pv.z, pv.w, po);
        *(float4*)&out[(row0 + ro) * T_STEPS + (T_STEPS - 4)] = pv;
    }
}

extern "C" void kernel_launch(void* const* d_in, const int* in_sizes, int n_in,
                              void* d_out, int out_size, void* d_ws, size_t ws_size,
                              hipStream_t stream) {
    const float* X  = (const float*)d_in[0];
    const float* y0 = (const float*)d_in[1];
    const float* W1 = (const float*)d_in[2];
    const float* b1 = (const float*)d_in[3];
    const float* W2 = (const float*)d_in[4];
    const float* b2 = (const float*)d_in[5];
    float* out = (float*)d_out;

    dim3 grid(B_TOT / 16);   // 1024 blocks x 4 waves
    dim3 block(64 * NW);
    narx_v6<<<grid, block, 0, stream>>>(X, y0, W1, b1, W2, b2, out);
}